// Round 3
// baseline (956.559 us; speedup 1.0000x reference)
//
#include <hip/hip_runtime.h>
#include <stdint.h>

#define T_LEN 256
#define BATCH 64
#define EDIM  512
#define HDIM  256      // hidden per direction
#define GDIM  1024     // 4*HDIM
#define KTAG  7
#define NEGV  -10000.0f

using u16 = unsigned short;
using u32 = unsigned int;
using u64 = unsigned long long;

typedef short    bf16x8 __attribute__((ext_vector_type(8)));
typedef float    f32x4  __attribute__((ext_vector_type(4)));

__device__ __forceinline__ float bflo(u32 u) { return __uint_as_float(u << 16); }
__device__ __forceinline__ float bfhi(u32 u) { return __uint_as_float(u & 0xffff0000u); }
__device__ __forceinline__ float bf2f(u16 u) { return __uint_as_float(((u32)u) << 16); }
__device__ __forceinline__ u16 f2bf(float f) {
    u32 x = __float_as_uint(f);
    u32 r = x + 0x7fffu + ((x >> 16) & 1u);   // round-to-nearest-even
    return (u16)(r >> 16);
}
__device__ __forceinline__ u32 pack2(float a, float b) {
    return (u32)f2bf(a) | ((u32)f2bf(b) << 16);
}
// fast sigmoid / tanh (rel err ~1e-5, far below bf16 input noise)
__device__ __forceinline__ float fsig(float x)  { return __builtin_amdgcn_rcpf(1.f + __expf(-x)); }
__device__ __forceinline__ float ftanh(float x) { return 1.f - 2.f * __builtin_amdgcn_rcpf(1.f + __expf(2.f * x)); }

__device__ __forceinline__ int dot4i8(int a, int b, int c) {
#if __has_builtin(__builtin_amdgcn_sdot4)
    return __builtin_amdgcn_sdot4(a, b, c, false);     // v_dot4_i32_i8
#else
    c += (int)(signed char)(a & 0xff)         * (int)(signed char)(b & 0xff);
    c += (int)(signed char)((a >> 8) & 0xff)  * (int)(signed char)((b >> 8) & 0xff);
    c += (int)(signed char)((a >> 16) & 0xff) * (int)(signed char)((b >> 16) & 0xff);
    c += (int)(signed char)(a >> 24)          * (int)(signed char)(b >> 24);
    return c;
#endif
}

// light barrier: order LDS only; global loads/stores stay in flight (no vmcnt drain)
__device__ __forceinline__ void bar_lds() {
    asm volatile("s_waitcnt lgkmcnt(0)" ::: "memory");
    __builtin_amdgcn_s_barrier();
    asm volatile("" ::: "memory");
}

// async global->LDS, 16B per lane; LDS dest must be linear (base + lane*16)
__device__ __forceinline__ void gload_lds16(const void* g, void* l) {
    __builtin_amdgcn_global_load_lds((const __attribute__((address_space(1))) u32*)g,
                                     (__attribute__((address_space(3))) u32*)l, 16, 0, 0);
}

// ---------------- embedding gather+convert: x[tb][e] = bf16(emb[sent[tb]][e]) ----------------
__global__ __launch_bounds__(64) void embed_k(const int* __restrict__ sent,
                                              const float* __restrict__ emb,
                                              u16* __restrict__ X) {
    int tb = blockIdx.x;
    int tok = sent[tb];
    const float4* src = (const float4*)(emb + (size_t)tok * EDIM);
    float4 a = src[threadIdx.x * 2];
    float4 b = src[threadIdx.x * 2 + 1];
    uint4 o;
    o.x = pack2(a.x, a.y); o.y = pack2(a.z, a.w);
    o.z = pack2(b.x, b.y); o.w = pack2(b.z, b.w);
    ((uint4*)(X + (size_t)tb * EDIM))[threadIdx.x] = o;
}

// ---------------- convert w_ih f32 -> bf16, same layout [2][2][1024][512] ----------------
__global__ __launch_bounds__(256) void conv_wih(const float* __restrict__ W,
                                                u16* __restrict__ WB) {
    int g = blockIdx.x * 256 + threadIdx.x;          // 262144 groups of 8
    const float4* src = (const float4*)(W + (size_t)g * 8);
    float4 a = src[0], b = src[1];
    uint4 o;
    o.x = pack2(a.x, a.y); o.y = pack2(a.z, a.w);
    o.z = pack2(b.x, b.y); o.w = pack2(b.z, b.w);
    *(uint4*)(WB + (size_t)g * 8) = o;
}

// ---- quantize w_hh f32 [4][1024][256] -> int8 WQ[((ld*4+r)*16 + c8)*256 + j] uint4 + SCL ----
// chunk c8 (0..15) of row holds k = c8*16 .. c8*16+16.  SCL[ld*1024+row] = rowmax/127.
__global__ __launch_bounds__(256) void repack_whh_i8(const float* __restrict__ Whh,
                                                     uint4* __restrict__ WQ,
                                                     float* __restrict__ SCL) {
    int g  = blockIdx.x * 256 + threadIdx.x;    // 4096 rows
    int ld = g >> 10, row = g & 1023;
    const float* src = Whh + ((size_t)ld * GDIM + row) * HDIM;
    float m = 1e-30f;
    for (int k4 = 0; k4 < 64; ++k4) {
        float4 w = ((const float4*)src)[k4];
        m = fmaxf(m, fmaxf(fmaxf(fabsf(w.x), fabsf(w.y)), fmaxf(fabsf(w.z), fabsf(w.w))));
    }
    float inv = 127.f / m;
    SCL[ld * GDIM + row] = m / 127.f;
    int r = row >> 8, j = row & 255;
    for (int c8 = 0; c8 < 16; ++c8) {           // 16-byte chunks
        u32 dw[4];
        #pragma unroll
        for (int d4 = 0; d4 < 4; ++d4) {
            u32 p = 0;
            #pragma unroll
            for (int bb = 0; bb < 4; ++bb) {
                float w = src[c8 * 16 + d4 * 4 + bb];
                int q = (int)rintf(w * inv);
                q = q > 127 ? 127 : (q < -127 ? -127 : q);
                p |= ((u32)(q & 0xff)) << (8 * bb);
            }
            dw[d4] = p;
        }
        WQ[(size_t)(((ld * 4 + r) * 16 + c8) * 256 + j)] =
            (uint4){dw[0], dw[1], dw[2], dw[3]};
    }
}

// ------------- xg = x @ w_ih^T + b_ih + b_hh -------------
// 128x128 tile, BK=64, double-buffered gload_lds staging, 2-phase pipeline:
// STAGE(t+1) issued BEFORE compute(t); one __syncthreads per K-tile (its vmcnt(0)
// drain lands after compute hid the load latency). K-accumulation order unchanged.
__global__ __launch_bounds__(256, 2) void gemm_xg(const u16* __restrict__ A,    // [16384][512] bf16
                                                  const u16* __restrict__ W,    // [2][1024][512] bf16
                                                  const float* __restrict__ Bih,// [2][1024] f32
                                                  const float* __restrict__ Bhh,
                                                  u16* __restrict__ XG) {       // [2][16384][1024] bf16
    const int d    = blockIdx.z;
    const int brow = blockIdx.x;               // 0..127 (M tiles)
    const int bcol = blockIdx.y;               // 0..7   (N tiles)
    const int tid  = threadIdx.x;
    const int lane = tid & 63;
    const int wv   = tid >> 6;                 // 4 waves: 2x2 of 64x64
    const int l15  = lane & 15;
    const int quad = lane >> 4;
    const int wr   = wv >> 1, wc = wv & 1;

    __shared__ u16 As[2][128 * 64];            // 2 x 16 KB, linear (gload_lds dest)
    __shared__ u16 Bs[2][128 * 64];            // 2 x 16 KB

    const u16* Wd = W + (size_t)d * GDIM * EDIM;
    const int srow = tid >> 3;                 // staging: 32 rows / issue
    const int scol = (tid & 7) * 8;            // u16 units (16 B per lane)
    const u16* ga = A  + (size_t)(brow * 128 + srow) * EDIM + scol;
    const u16* gb = Wd + (size_t)(bcol * 128 + srow) * EDIM + scol;
    const int loff = srow * 64 + scol;

    f32x4 acc[4][4];
    #pragma unroll
    for (int mt = 0; mt < 4; ++mt)
        #pragma unroll
        for (int nt = 0; nt < 4; ++nt)
            acc[mt][nt] = (f32x4){0.f, 0.f, 0.f, 0.f};

    // prologue: stage tile 0
    #pragma unroll
    for (int it = 0; it < 4; ++it) {
        gload_lds16(ga + (size_t)(it * 32) * EDIM, &As[0][loff + it * 32 * 64]);
        gload_lds16(gb + (size_t)(it * 32) * EDIM, &Bs[0][loff + it * 32 * 64]);
    }
    __syncthreads();

    int cur = 0;
    for (int t = 0; t < 8; ++t) {
        if (t < 7) {                           // issue next tile into other buffer
            int k0 = (t + 1) * 64;
            #pragma unroll
            for (int it = 0; it < 4; ++it) {
                gload_lds16(ga + (size_t)(it * 32) * EDIM + k0, &As[cur ^ 1][loff + it * 32 * 64]);
                gload_lds16(gb + (size_t)(it * 32) * EDIM + k0, &Bs[cur ^ 1][loff + it * 32 * 64]);
            }
        }
        const u16* Ab = As[cur];
        const u16* Bb = Bs[cur];
        #pragma unroll
        for (int ks = 0; ks < 2; ++ks) {
            bf16x8 av[4], bv[4];
            #pragma unroll
            for (int mt = 0; mt < 4; ++mt)
                av[mt] = *(const bf16x8*)(Ab + (wr * 64 + mt * 16 + l15) * 64 + ks * 32 + quad * 8);
            #pragma unroll
            for (int nt = 0; nt < 4; ++nt)
                bv[nt] = *(const bf16x8*)(Bb + (wc * 64 + nt * 16 + l15) * 64 + ks * 32 + quad * 8);
            #pragma unroll
            for (int mt = 0; mt < 4; ++mt)
                #pragma unroll
                for (int nt = 0; nt < 4; ++nt)
                    acc[mt][nt] = __builtin_amdgcn_mfma_f32_16x16x32_bf16(av[mt], bv[nt], acc[mt][nt], 0, 0, 0);
        }
        __syncthreads();                       // drains vmcnt: next tile ready, reads done
        cur ^= 1;
    }

    u16* xgd = XG + (size_t)d * ((size_t)16384 * GDIM);
    #pragma unroll
    for (int nt = 0; nt < 4; ++nt) {
        int col = bcol * 128 + wc * 64 + nt * 16 + l15;   // C/D: col=lane&15, row=quad*4+reg
        float bias = Bih[d * GDIM + col] + Bhh[d * GDIM + col];
        #pragma unroll
        for (int mt = 0; mt < 4; ++mt) {
            int row0 = brow * 128 + wr * 64 + mt * 16 + quad * 4;
            #pragma unroll
            for (int r = 0; r < 4; ++r)
                xgd[(size_t)(row0 + r) * GDIM + col] = f2bf(acc[mt][nt][r] + bias);
        }
    }
}

// ------------- recurrent scan, int8 register-resident weights -------------
// 128 blocks = (d,b); 1024 threads: j = tid&255, q = tid>>8 (K-quarter).
// Thread holds wq rows {j,256+j,512+j,768+j} for its 64-wide K-quarter: 64 VGPRs.
// R1/R2 post-mortem: VGPR_Count=56 both rounds -> the backend SINKS the
// loop-invariant weight loads into the loop, re-fetching 256 KB/block/step from
// L2 (16 blocks/XCD x 256 KB = 4 MB/step/XCD at ~4.3 TB/s = ~2330 cyc/step =
// the entire observed step time). Occupancy attributes only change the budget;
// they can't forbid rematerialization. Fix: a zero-instruction asm "+v" pin on
// every weight dword INSIDE the loop — the asm "redefines" the value each
// iteration, so a sunk reload is illegal and all 64 dwords must stay in VGPRs.
#define PIN4(u) asm volatile("" : "+v"((u).x), "+v"((u).y), "+v"((u).z), "+v"((u).w))
__global__ __attribute__((amdgpu_waves_per_eu(4, 4))) __launch_bounds__(1024)
void lstm_scan_i8(
        const u16* __restrict__ XG,        // [2][16384][1024] bf16 (this layer)
        const uint4* __restrict__ WQ,      // this layer's int8 slice
        const float* __restrict__ SCL,     // [2][1024] weight LSB
        const float* __restrict__ H0,      // [2][64][256] f32
        const float* __restrict__ C0,
        u16* __restrict__ XOUT) {          // [16384][512] bf16
    const int b   = blockIdx.x & 63;
    const int d   = blockIdx.x >> 6;
    const int tid = threadIdx.x;
    const int j   = tid & 255;
    const int q   = tid >> 8;              // K-quarter 0..3

    __shared__ uint4  hq[2][16];           // double-buffered int8 h (2 x 256 B)
    __shared__ float4 psv[4 * 256];        // per-quarter integer partials (exact f32), 16 KB

    // ---- load weights into registers (coalesced: lane-adjacent j) ----
    uint4 Wr[4][4];
    #pragma unroll
    for (int r = 0; r < 4; ++r)
        #pragma unroll
        for (int c = 0; c < 4; ++c)
            Wr[r][c] = WQ[(size_t)(((d * 4 + r) * 16 + q * 4 + c) * 256 + j)];

    float scl0 = 0.f, scl1 = 0.f, scl2 = 0.f, scl3 = 0.f, cst = 0.f;
    if (q == 0) {
        scl0 = SCL[d * GDIM + 0 * 256 + j];
        scl1 = SCL[d * GDIM + 1 * 256 + j];
        scl2 = SCL[d * GDIM + 2 * 256 + j];
        scl3 = SCL[d * GDIM + 3 * 256 + j];
        float h0v = H0[((size_t)d * BATCH + b) * HDIM + j];
        cst       = C0[((size_t)d * BATCH + b) * HDIM + j];
        int qz = (int)rintf(h0v * 31.75f);                 // scale 127/4 (|h0| can exceed 1)
        qz = qz > 127 ? 127 : (qz < -127 ? -127 : qz);
        ((signed char*)hq)[j] = (signed char)qz;           // buffer 0
    }
    __syncthreads();

    const u16* xgp = XG + (size_t)d * ((size_t)16384 * GDIM) + (size_t)b * GDIM + j;
    // even/odd register pipeline: xe used at even steps, xo at odd; reload 2 steps ahead
    u16 xe[4], xo[4];
    if (q == 0) {
        int t0 = d ? T_LEN - 1 : 0;
        int t1 = d ? T_LEN - 2 : 1;
        #pragma unroll
        for (int r = 0; r < 4; ++r) xe[r] = xgp[(size_t)t0 * (BATCH * GDIM) + r * 256];
        #pragma unroll
        for (int r = 0; r < 4; ++r) xo[r] = xgp[(size_t)t1 * (BATCH * GDIM) + r * 256];
    }

    float hs = 4.f / 127.f;                // h LSB for step 0 input h; 1/127 afterwards

#define SCAN_SUBSTEP(S, XA, RB, WB)                                                     \
    {                                                                                   \
        const int t_ = d ? (T_LEN - 1 - (S)) : (S);                                     \
        const uint4* hb = (const uint4*)hq + (RB) * 16 + q * 4;                         \
        uint4 hv[4];                                                                    \
        _Pragma("unroll")                                                               \
        for (int c = 0; c < 4; ++c) hv[c] = hb[c];          /* wave-uniform: broadcast */\
        int a0 = 0, a1 = 0, a2 = 0, a3 = 0;                                             \
        _Pragma("unroll")                                                               \
        for (int c = 0; c < 4; ++c) {                                                   \
            a0 = dot4i8(Wr[0][c].x, hv[c].x, a0);                                       \
            a0 = dot4i8(Wr[0][c].y, hv[c].y, a0);                                       \
            a0 = dot4i8(Wr[0][c].z, hv[c].z, a0);                                       \
            a0 = dot4i8(Wr[0][c].w, hv[c].w, a0);                                       \
            a1 = dot4i8(Wr[1][c].x, hv[c].x, a1);                                       \
            a1 = dot4i8(Wr[1][c].y, hv[c].y, a1);                                       \
            a1 = dot4i8(Wr[1][c].z, hv[c].z, a1);                                       \
            a1 = dot4i8(Wr[1][c].w, hv[c].w, a1);                                       \
            a2 = dot4i8(Wr[2][c].x, hv[c].x, a2);                                       \
            a2 = dot4i8(Wr[2][c].y, hv[c].y, a2);                                       \
            a2 = dot4i8(Wr[2][c].z, hv[c].z, a2);                                       \
            a2 = dot4i8(Wr[2][c].w, hv[c].w, a2);                                       \
            a3 = dot4i8(Wr[3][c].x, hv[c].x, a3);                                       \
            a3 = dot4i8(Wr[3][c].y, hv[c].y, a3);                                       \
            a3 = dot4i8(Wr[3][c].z, hv[c].z, a3);                                       \
            a3 = dot4i8(Wr[3][c].w, hv[c].w, a3);                                       \
        }                                                                               \
        /* |quarter partial| < 2^21 -> f32-exact; sums of 4 stay < 2^24 -> exact */     \
        psv[q * 256 + j] = (float4){(float)a0, (float)a1, (float)a2, (float)a3};        \
        bar_lds();                                                                      \
        if (q == 0) {                                                                   \
            float4 p0 = psv[j], p1 = psv[256 + j], p2 = psv[512 + j], p3 = psv[768 + j];\
            float g0 = bf2f(XA[0]) + (p0.x + p1.x + p2.x + p3.x) * (scl0 * hs);         \
            float g1 = bf2f(XA[1]) + (p0.y + p1.y + p2.y + p3.y) * (scl1 * hs);         \
            float g2 = bf2f(XA[2]) + (p0.z + p1.z + p2.z + p3.z) * (scl2 * hs);         \
            float g3 = bf2f(XA[3]) + (p0.w + p1.w + p2.w + p3.w) * (scl3 * hs);         \
            float iv = fsig(g0), fv = fsig(g1), gv = ftanh(g2), ov = fsig(g3);          \
            cst = fv * cst + iv * gv;                                                   \
            float h = ov * ftanh(cst);                                                  \
            XOUT[((size_t)t_ * BATCH + b) * EDIM + d * HDIM + j] = f2bf(h);             \
            int qz = (int)rintf(h * 127.f);                /* |h|<1: scale 1/127 */     \
            qz = qz > 127 ? 127 : (qz < -127 ? -127 : qz);                              \
            ((signed char*)hq)[(WB) * 256 + j] = (signed char)qz;                       \
            int s2 = ((S) + 2 < T_LEN) ? (S) + 2 : T_LEN - 1;                           \
            int t2 = d ? (T_LEN - 1 - s2) : s2;                                         \
            _Pragma("unroll")                                                           \
            for (int r = 0; r < 4; ++r)                                                 \
                XA[r] = xgp[(size_t)t2 * (BATCH * GDIM) + r * 256];                     \
        }                                                                               \
        bar_lds();                                                                      \
        hs = 1.f / 127.f;                                                               \
    }

    for (int s = 0; s < T_LEN; s += 2) {
        // force weight residency: zero-inst asm redefines each dword every
        // iteration -> backend cannot sink/remat the global loads into the loop
        #pragma unroll
        for (int r = 0; r < 4; ++r)
            #pragma unroll
            for (int c = 0; c < 4; ++c)
                PIN4(Wr[r][c]);
        SCAN_SUBSTEP(s,     xe, 0, 1);
        SCAN_SUBSTEP(s + 1, xo, 1, 0);
    }
#undef SCAN_SUBSTEP
}

// ------------- feats[tb][k] = x[tb] . w_out[k] + b_out[k]  (one wave per tb) -------------
__global__ __launch_bounds__(64) void feats_k(const u16* __restrict__ X,      // [16384][512] bf16
                                              const float* __restrict__ Wout, // [7][512] f32
                                              const float* __restrict__ Bout, // [7] f32
                                              float* __restrict__ F) {        // [16384][8] f32
    int tb = blockIdx.x, lane = threadIdx.x;
    uint4 xv = ((const uint4*)(X + (size_t)tb * EDIM))[lane];   // 8 bf16 of x
    float xf[8];
    xf[0] = bflo(xv.x); xf[1] = bfhi(xv.x); xf[2] = bflo(xv.y); xf[3] = bfhi(xv.y);
    xf[4] = bflo(xv.z); xf[5] = bfhi(xv.z); xf[6] = bflo(xv.w); xf[7] = bfhi(xv.w);
    #pragma unroll
    for (int k = 0; k < KTAG; ++k) {
        const float4* wpo = (const float4*)(Wout + (size_t)k * EDIM) + lane * 2;
        float4 wa = wpo[0], wb = wpo[1];
        float p = 0.0f;
        p = fmaf(xf[0], wa.x, p); p = fmaf(xf[1], wa.y, p);
        p = fmaf(xf[2], wa.z, p); p = fmaf(xf[3], wa.w, p);
        p = fmaf(xf[4], wb.x, p); p = fmaf(xf[5], wb.y, p);
        p = fmaf(xf[6], wb.z, p); p = fmaf(xf[7], wb.w, p);
        #pragma unroll
        for (int off = 32; off > 0; off >>= 1) p += __shfl_xor(p, off, 64);
        if (lane == 0) F[tb * 8 + k] = p + Bout[k];
    }
}

// ------------- Viterbi: one wave, lane = batch; byte-packed backpointers -------------
__global__ __launch_bounds__(64) void viterbi_k(const float* __restrict__ F,
                                                const float* __restrict__ Trans, // [7][7] next,prev
                                                u64* __restrict__ BP8,           // [256][64]
                                                float* __restrict__ OUT) {       // 16448 floats
    int b = threadIdx.x;
    float tr[KTAG][KTAG];
    #pragma unroll
    for (int n = 0; n < KTAG; ++n)
        #pragma unroll
        for (int p = 0; p < KTAG; ++p)
            tr[n][p] = Trans[n * KTAG + p];

    float v[KTAG];
    #pragma unroll
    for (int k = 0; k < KTAG; ++k) v[k] = (k == 5) ? 0.0f : NEGV;  // START=5

    float cf[KTAG], nf[KTAG];
    #pragma unroll
    for (int n = 0; n < KTAG; ++n) cf[n] = F[b * 8 + n];           // t=0

    for (int t = 0; t < T_LEN; ++t) {
        int tp = (t + 1 < T_LEN) ? t + 1 : t;
        #pragma unroll
        for (int n = 0; n < KTAG; ++n) nf[n] = F[((tp)*BATCH + b) * 8 + n];  // prefetch t+1

        u64 pk = 0;
        float nv[KTAG];
        #pragma unroll
        for (int n = 0; n < KTAG; ++n) {
            float best = v[0] + tr[n][0]; int bi = 0;
            #pragma unroll
            for (int p = 1; p < KTAG; ++p) {
                float s = v[p] + tr[n][p];
                if (s > best) { best = s; bi = p; }   // strict > == np.argmax first-max
            }
            pk |= ((u64)bi) << (8 * n);
            nv[n] = best + cf[n];
        }
        BP8[t * BATCH + b] = pk;
        #pragma unroll
        for (int n = 0; n < KTAG; ++n) { v[n] = nv[n]; cf[n] = nf[n]; }
    }
    float bs = v[0] + tr[6][0]; int tag = 0;          // STOP=6
    #pragma unroll
    for (int k = 1; k < KTAG; ++k) {
        float s = v[k] + tr[6][k];
        if (s > bs) { bs = s; tag = k; }
    }
    OUT[T_LEN * BATCH + b] = bs;                      // path_score [B]
    for (int t = T_LEN - 1; t >= 0; --t) {
        OUT[(size_t)b * T_LEN + t] = (float)tag;      // best_path [B][T]
        tag = (int)((BP8[t * BATCH + b] >> (8 * tag)) & 0xff);
    }
}

extern "C" void kernel_launch(void* const* d_in, const int* in_sizes, int n_in,
                              void* d_out, int out_size, void* d_ws, size_t ws_size,
                              hipStream_t stream) {
    const int*   sent  = (const int*)d_in[0];
    const float* emb   = (const float*)d_in[1];   // [50000][512]
    const float* w_ih  = (const float*)d_in[2];   // [2][2][1024][512]
    const float* w_hh  = (const float*)d_in[3];   // [2][2][1024][256]
    const float* b_ih  = (const float*)d_in[4];   // [2][2][1024]
    const float* b_hh  = (const float*)d_in[5];
    const float* w_out = (const float*)d_in[6];   // [7][512]
    const float* b_out = (const float*)d_in[7];   // [7]
    const float* trans = (const float*)d_in[8];   // [7][7]
    const float* h0    = (const float*)d_in[9];   // [4][64][256]
    const float* c0    = (const float*)d_in[10];
    float* out = (float*)d_out;

    char* ws = (char*)d_ws;
    u16*   xg    = (u16*)(ws);                       // 64 MB  [2][16384][1024] bf16
    u16*   x     = (u16*)(ws + 67108864);            // 16 MB  [16384][512] bf16
    u16*   wihB  = (u16*)(ws + 83886080);            // 4 MB   bf16 w_ih
    uint4* wq    = (uint4*)(ws + 88080384);          // 1 MB   int8 w_hh (packed)
    float* scl   = (float*)(ws + 89128960);          // 16 KB  scales
    float* feats = (float*)(ws + 89145344);          // 512 KB
    u64*   bp8   = (u64*)(ws + 89669632);            // 128 KB

    embed_k<<<16384, 64, 0, stream>>>(sent, emb, x);
    conv_wih<<<1024, 256, 0, stream>>>(w_ih, wihB);
    repack_whh_i8<<<16, 256, 0, stream>>>(w_hh, wq, scl);

    for (int l = 0; l < 2; ++l) {
        gemm_xg<<<dim3(128, 8, 2), 256, 0, stream>>>(
            x, wihB + (size_t)l * 2 * GDIM * EDIM,
            b_ih + (size_t)l * 2 * GDIM, b_hh + (size_t)l * 2 * GDIM, xg);
        // layer l's weights start at ld=2l; WQ ld-stride = 16384 uint4 -> offset l*32768
        lstm_scan_i8<<<128, 1024, 0, stream>>>(
            xg, wq + (size_t)l * 32768, scl + (size_t)l * 2048,
            h0 + (size_t)l * 2 * BATCH * HDIM, c0 + (size_t)l * 2 * BATCH * HDIM, x);
    }

    feats_k<<<16384, 64, 0, stream>>>(x, w_out, b_out, feats);
    viterbi_k<<<1, 64, 0, stream>>>(feats, trans, bp8, out);
}

// Round 4
// 923.371 us; speedup vs baseline: 1.0359x; 1.0359x over previous
//
#include <hip/hip_runtime.h>
#include <stdint.h>

#define T_LEN 256
#define BATCH 64
#define EDIM  512
#define HDIM  256      // hidden per direction
#define GDIM  1024     // 4*HDIM
#define KTAG  7
#define NEGV  -10000.0f

using u16 = unsigned short;
using u32 = unsigned int;
using u64 = unsigned long long;

typedef short    bf16x8 __attribute__((ext_vector_type(8)));
typedef float    f32x4  __attribute__((ext_vector_type(4)));

__device__ __forceinline__ float bflo(u32 u) { return __uint_as_float(u << 16); }
__device__ __forceinline__ float bfhi(u32 u) { return __uint_as_float(u & 0xffff0000u); }
__device__ __forceinline__ float bf2f(u16 u) { return __uint_as_float(((u32)u) << 16); }
__device__ __forceinline__ u16 f2bf(float f) {
    u32 x = __float_as_uint(f);
    u32 r = x + 0x7fffu + ((x >> 16) & 1u);   // round-to-nearest-even
    return (u16)(r >> 16);
}
__device__ __forceinline__ u32 pack2(float a, float b) {
    return (u32)f2bf(a) | ((u32)f2bf(b) << 16);
}
// fast sigmoid / tanh (rel err ~1e-5, far below bf16 input noise)
__device__ __forceinline__ float fsig(float x)  { return __builtin_amdgcn_rcpf(1.f + __expf(-x)); }
__device__ __forceinline__ float ftanh(float x) { return 1.f - 2.f * __builtin_amdgcn_rcpf(1.f + __expf(2.f * x)); }

__device__ __forceinline__ int dot4i8(int a, int b, int c) {
#if __has_builtin(__builtin_amdgcn_sdot4)
    return __builtin_amdgcn_sdot4(a, b, c, false);     // v_dot4_i32_i8
#else
    c += (int)(signed char)(a & 0xff)         * (int)(signed char)(b & 0xff);
    c += (int)(signed char)((a >> 8) & 0xff)  * (int)(signed char)((b >> 8) & 0xff);
    c += (int)(signed char)((a >> 16) & 0xff) * (int)(signed char)((b >> 16) & 0xff);
    c += (int)(signed char)(a >> 24)          * (int)(signed char)(b >> 24);
    return c;
#endif
}

// light barrier: order LDS only; global loads/stores stay in flight (no vmcnt drain)
__device__ __forceinline__ void bar_lds() {
    asm volatile("s_waitcnt lgkmcnt(0)" ::: "memory");
    __builtin_amdgcn_s_barrier();
    asm volatile("" ::: "memory");
}

// async global->LDS, 16B per lane; LDS dest must be linear (base + lane*16)
__device__ __forceinline__ void gload_lds16(const void* g, void* l) {
    __builtin_amdgcn_global_load_lds((const __attribute__((address_space(1))) u32*)g,
                                     (__attribute__((address_space(3))) u32*)l, 16, 0, 0);
}

// ---------------- embedding gather+convert: x[tb][e] = bf16(emb[sent[tb]][e]) ----------------
__global__ __launch_bounds__(64) void embed_k(const int* __restrict__ sent,
                                              const float* __restrict__ emb,
                                              u16* __restrict__ X) {
    int tb = blockIdx.x;
    int tok = sent[tb];
    const float4* src = (const float4*)(emb + (size_t)tok * EDIM);
    float4 a = src[threadIdx.x * 2];
    float4 b = src[threadIdx.x * 2 + 1];
    uint4 o;
    o.x = pack2(a.x, a.y); o.y = pack2(a.z, a.w);
    o.z = pack2(b.x, b.y); o.w = pack2(b.z, b.w);
    ((uint4*)(X + (size_t)tb * EDIM))[threadIdx.x] = o;
}

// ---------------- convert w_ih f32 -> bf16, same layout [2][2][1024][512] ----------------
__global__ __launch_bounds__(256) void conv_wih(const float* __restrict__ W,
                                                u16* __restrict__ WB) {
    int g = blockIdx.x * 256 + threadIdx.x;          // 262144 groups of 8
    const float4* src = (const float4*)(W + (size_t)g * 8);
    float4 a = src[0], b = src[1];
    uint4 o;
    o.x = pack2(a.x, a.y); o.y = pack2(a.z, a.w);
    o.z = pack2(b.x, b.y); o.w = pack2(b.z, b.w);
    *(uint4*)(WB + (size_t)g * 8) = o;
}

// ---- quantize w_hh f32 [4][1024][256] -> int8 WQ[((ld*4+r)*16 + c8)*256 + j] uint4 + SCL ----
// chunk c8 (0..15) of row holds k = c8*16 .. c8*16+16.  SCL[ld*1024+row] = rowmax/127.
__global__ __launch_bounds__(256) void repack_whh_i8(const float* __restrict__ Whh,
                                                     uint4* __restrict__ WQ,
                                                     float* __restrict__ SCL) {
    int g  = blockIdx.x * 256 + threadIdx.x;    // 4096 rows
    int ld = g >> 10, row = g & 1023;
    const float* src = Whh + ((size_t)ld * GDIM + row) * HDIM;
    float m = 1e-30f;
    for (int k4 = 0; k4 < 64; ++k4) {
        float4 w = ((const float4*)src)[k4];
        m = fmaxf(m, fmaxf(fmaxf(fabsf(w.x), fabsf(w.y)), fmaxf(fabsf(w.z), fabsf(w.w))));
    }
    float inv = 127.f / m;
    SCL[ld * GDIM + row] = m / 127.f;
    int r = row >> 8, j = row & 255;
    for (int c8 = 0; c8 < 16; ++c8) {           // 16-byte chunks
        u32 dw[4];
        #pragma unroll
        for (int d4 = 0; d4 < 4; ++d4) {
            u32 p = 0;
            #pragma unroll
            for (int bb = 0; bb < 4; ++bb) {
                float w = src[c8 * 16 + d4 * 4 + bb];
                int q = (int)rintf(w * inv);
                q = q > 127 ? 127 : (q < -127 ? -127 : q);
                p |= ((u32)(q & 0xff)) << (8 * bb);
            }
            dw[d4] = p;
        }
        WQ[(size_t)(((ld * 4 + r) * 16 + c8) * 256 + j)] =
            (uint4){dw[0], dw[1], dw[2], dw[3]};
    }
}

// ------------- xg = x @ w_ih^T + b_ih + b_hh -------------
// 128x128 tile, BK=64, double-buffered gload_lds staging, 2-phase pipeline.
__global__ __launch_bounds__(256, 2) void gemm_xg(const u16* __restrict__ A,    // [16384][512] bf16
                                                  const u16* __restrict__ W,    // [2][1024][512] bf16
                                                  const float* __restrict__ Bih,// [2][1024] f32
                                                  const float* __restrict__ Bhh,
                                                  u16* __restrict__ XG) {       // [2][16384][1024] bf16
    const int d    = blockIdx.z;
    const int brow = blockIdx.x;               // 0..127 (M tiles)
    const int bcol = blockIdx.y;               // 0..7   (N tiles)
    const int tid  = threadIdx.x;
    const int lane = tid & 63;
    const int wv   = tid >> 6;                 // 4 waves: 2x2 of 64x64
    const int l15  = lane & 15;
    const int quad = lane >> 4;
    const int wr   = wv >> 1, wc = wv & 1;

    __shared__ u16 As[2][128 * 64];            // 2 x 16 KB, linear (gload_lds dest)
    __shared__ u16 Bs[2][128 * 64];            // 2 x 16 KB

    const u16* Wd = W + (size_t)d * GDIM * EDIM;
    const int srow = tid >> 3;                 // staging: 32 rows / issue
    const int scol = (tid & 7) * 8;            // u16 units (16 B per lane)
    const u16* ga = A  + (size_t)(brow * 128 + srow) * EDIM + scol;
    const u16* gb = Wd + (size_t)(bcol * 128 + srow) * EDIM + scol;
    const int loff = srow * 64 + scol;

    f32x4 acc[4][4];
    #pragma unroll
    for (int mt = 0; mt < 4; ++mt)
        #pragma unroll
        for (int nt = 0; nt < 4; ++nt)
            acc[mt][nt] = (f32x4){0.f, 0.f, 0.f, 0.f};

    // prologue: stage tile 0
    #pragma unroll
    for (int it = 0; it < 4; ++it) {
        gload_lds16(ga + (size_t)(it * 32) * EDIM, &As[0][loff + it * 32 * 64]);
        gload_lds16(gb + (size_t)(it * 32) * EDIM, &Bs[0][loff + it * 32 * 64]);
    }
    __syncthreads();

    int cur = 0;
    for (int t = 0; t < 8; ++t) {
        if (t < 7) {                           // issue next tile into other buffer
            int k0 = (t + 1) * 64;
            #pragma unroll
            for (int it = 0; it < 4; ++it) {
                gload_lds16(ga + (size_t)(it * 32) * EDIM + k0, &As[cur ^ 1][loff + it * 32 * 64]);
                gload_lds16(gb + (size_t)(it * 32) * EDIM + k0, &Bs[cur ^ 1][loff + it * 32 * 64]);
            }
        }
        const u16* Ab = As[cur];
        const u16* Bb = Bs[cur];
        #pragma unroll
        for (int ks = 0; ks < 2; ++ks) {
            bf16x8 av[4], bv[4];
            #pragma unroll
            for (int mt = 0; mt < 4; ++mt)
                av[mt] = *(const bf16x8*)(Ab + (wr * 64 + mt * 16 + l15) * 64 + ks * 32 + quad * 8);
            #pragma unroll
            for (int nt = 0; nt < 4; ++nt)
                bv[nt] = *(const bf16x8*)(Bb + (wc * 64 + nt * 16 + l15) * 64 + ks * 32 + quad * 8);
            #pragma unroll
            for (int mt = 0; mt < 4; ++mt)
                #pragma unroll
                for (int nt = 0; nt < 4; ++nt)
                    acc[mt][nt] = __builtin_amdgcn_mfma_f32_16x16x32_bf16(av[mt], bv[nt], acc[mt][nt], 0, 0, 0);
        }
        __syncthreads();                       // drains vmcnt: next tile ready, reads done
        cur ^= 1;
    }

    u16* xgd = XG + (size_t)d * ((size_t)16384 * GDIM);
    #pragma unroll
    for (int nt = 0; nt < 4; ++nt) {
        int col = bcol * 128 + wc * 64 + nt * 16 + l15;   // C/D: col=lane&15, row=quad*4+reg
        float bias = Bih[d * GDIM + col] + Bhh[d * GDIM + col];
        #pragma unroll
        for (int mt = 0; mt < 4; ++mt) {
            int row0 = brow * 128 + wr * 64 + mt * 16 + quad * 4;
            #pragma unroll
            for (int r = 0; r < 4; ++r)
                xgd[(size_t)(row0 + r) * GDIM + col] = f2bf(acc[mt][nt][r] + bias);
        }
    }
}

// ------------- recurrent scan, int8 weights: 3 gate-rows in regs + 1 row in LDS -------------
// 128 blocks = (d,b); 1024 threads: j = tid&255, q = tid>>8 (K-quarter).
// R1-R3 post-mortem: the allocator hard-caps this kernel at the <=64-VGPR tier
// because TWO 1024-thread workgroups fit per CU by LDS; all advisory attributes
// failed, and in-loop pins just forced scratch spills (R3). Structural fix:
//  (a) dynamic LDS = 82 KB > 80 KB  ->  only ONE workgroup fits per CU  ->
//      occupancy-driven VGPR cap rises to the 128 tier (16 waves/CU).
//  (b) weight rows i,f,g (48 VGPRs) in registers; row o (64 KB) lives in LDS.
//  (c) one-time opaque pin AFTER the loads, BEFORE the loop: values become
//      asm-defined registers -> reload/remat is illegal, and at budget 128 the
//      allocator keeps them resident instead of spilling.
// Integer dot order per accumulator unchanged -> bit-identical output.
#define PIN4(u) asm volatile("" : "+v"((u).x), "+v"((u).y), "+v"((u).z), "+v"((u).w))
__global__ __attribute__((amdgpu_waves_per_eu(4, 4))) __launch_bounds__(1024)
void lstm_scan_i8(
        const u16* __restrict__ XG,        // [2][16384][1024] bf16 (this layer)
        const uint4* __restrict__ WQ,      // this layer's int8 slice
        const float* __restrict__ SCL,     // [2][1024] weight LSB
        const float* __restrict__ H0,      // [2][64][256] f32
        const float* __restrict__ C0,
        u16* __restrict__ XOUT) {          // [16384][512] bf16
    const int b   = blockIdx.x & 63;
    const int d   = blockIdx.x >> 6;
    const int tid = threadIdx.x;
    const int j   = tid & 255;
    const int q   = tid >> 8;              // K-quarter 0..3

    extern __shared__ char smem[];
    uint4*  wlds = (uint4*)smem;                      // [16][256] o-gate row, 64 KB
    float4* psv  = (float4*)(smem + 65536);           // [4][256] partials, 16 KB
    uint4*  hq   = (uint4*)(smem + 65536 + 16384);    // [2][16] int8 h, 512 B

    // ---- weight rows 0..2 into registers (coalesced: lane-adjacent j) ----
    uint4 Wr[3][4];
    #pragma unroll
    for (int r = 0; r < 3; ++r)
        #pragma unroll
        for (int c = 0; c < 4; ++c)
            Wr[r][c] = WQ[(size_t)(((d * 4 + r) * 16 + q * 4 + c) * 256 + j)];
    // ---- weight row 3 into LDS ----
    #pragma unroll
    for (int c = 0; c < 4; ++c)
        wlds[(q * 4 + c) * 256 + j] = WQ[(size_t)(((d * 4 + 3) * 16 + q * 4 + c) * 256 + j)];

    // one-time opaque pin: Wr values are now asm-defined, not reloadable
    #pragma unroll
    for (int r = 0; r < 3; ++r)
        #pragma unroll
        for (int c = 0; c < 4; ++c)
            PIN4(Wr[r][c]);

    float scl0 = 0.f, scl1 = 0.f, scl2 = 0.f, scl3 = 0.f, cst = 0.f;
    if (q == 0) {
        scl0 = SCL[d * GDIM + 0 * 256 + j];
        scl1 = SCL[d * GDIM + 1 * 256 + j];
        scl2 = SCL[d * GDIM + 2 * 256 + j];
        scl3 = SCL[d * GDIM + 3 * 256 + j];
        asm volatile("" : "+v"(scl0), "+v"(scl1), "+v"(scl2), "+v"(scl3));
        float h0v = H0[((size_t)d * BATCH + b) * HDIM + j];
        cst       = C0[((size_t)d * BATCH + b) * HDIM + j];
        int qz = (int)rintf(h0v * 31.75f);                 // scale 127/4 (|h0| can exceed 1)
        qz = qz > 127 ? 127 : (qz < -127 ? -127 : qz);
        ((signed char*)hq)[j] = (signed char)qz;           // buffer 0
    }
    __syncthreads();

    const u16* xgp = XG + (size_t)d * ((size_t)16384 * GDIM) + (size_t)b * GDIM + j;
    // even/odd register pipeline: xe used at even steps, xo at odd; reload 2 steps ahead
    u16 xe[4], xo[4];
    if (q == 0) {
        int t0 = d ? T_LEN - 1 : 0;
        int t1 = d ? T_LEN - 2 : 1;
        #pragma unroll
        for (int r = 0; r < 4; ++r) xe[r] = xgp[(size_t)t0 * (BATCH * GDIM) + r * 256];
        #pragma unroll
        for (int r = 0; r < 4; ++r) xo[r] = xgp[(size_t)t1 * (BATCH * GDIM) + r * 256];
    }

    float hs = 4.f / 127.f;                // h LSB for step 0 input h; 1/127 afterwards

#define SCAN_SUBSTEP(S, XA, RB, WB)                                                     \
    {                                                                                   \
        const int t_ = d ? (T_LEN - 1 - (S)) : (S);                                     \
        const uint4* hb = hq + (RB) * 16 + q * 4;                                       \
        uint4 hv[4], w3[4];                                                             \
        _Pragma("unroll")                                                               \
        for (int c = 0; c < 4; ++c) hv[c] = hb[c];          /* wave-uniform: broadcast */\
        _Pragma("unroll")                                                               \
        for (int c = 0; c < 4; ++c) w3[c] = wlds[(q * 4 + c) * 256 + j];                \
        int a0 = 0, a1 = 0, a2 = 0, a3 = 0;                                             \
        _Pragma("unroll")                                                               \
        for (int c = 0; c < 4; ++c) {                                                   \
            a0 = dot4i8(Wr[0][c].x, hv[c].x, a0);                                       \
            a0 = dot4i8(Wr[0][c].y, hv[c].y, a0);                                       \
            a0 = dot4i8(Wr[0][c].z, hv[c].z, a0);                                       \
            a0 = dot4i8(Wr[0][c].w, hv[c].w, a0);                                       \
            a1 = dot4i8(Wr[1][c].x, hv[c].x, a1);                                       \
            a1 = dot4i8(Wr[1][c].y, hv[c].y, a1);                                       \
            a1 = dot4i8(Wr[1][c].z, hv[c].z, a1);                                       \
            a1 = dot4i8(Wr[1][c].w, hv[c].w, a1);                                       \
            a2 = dot4i8(Wr[2][c].x, hv[c].x, a2);                                       \
            a2 = dot4i8(Wr[2][c].y, hv[c].y, a2);                                       \
            a2 = dot4i8(Wr[2][c].z, hv[c].z, a2);                                       \
            a2 = dot4i8(Wr[2][c].w, hv[c].w, a2);                                       \
            a3 = dot4i8(w3[c].x, hv[c].x, a3);                                          \
            a3 = dot4i8(w3[c].y, hv[c].y, a3);                                          \
            a3 = dot4i8(w3[c].z, hv[c].z, a3);                                          \
            a3 = dot4i8(w3[c].w, hv[c].w, a3);                                          \
        }                                                                               \
        /* |quarter partial| < 2^21 -> f32-exact; sums of 4 stay < 2^24 -> exact */     \
        psv[q * 256 + j] = (float4){(float)a0, (float)a1, (float)a2, (float)a3};        \
        bar_lds();                                                                      \
        if (q == 0) {                                                                   \
            float4 p0 = psv[j], p1 = psv[256 + j], p2 = psv[512 + j], p3 = psv[768 + j];\
            float g0 = bf2f(XA[0]) + (p0.x + p1.x + p2.x + p3.x) * (scl0 * hs);         \
            float g1 = bf2f(XA[1]) + (p0.y + p1.y + p2.y + p3.y) * (scl1 * hs);         \
            float g2 = bf2f(XA[2]) + (p0.z + p1.z + p2.z + p3.z) * (scl2 * hs);         \
            float g3 = bf2f(XA[3]) + (p0.w + p1.w + p2.w + p3.w) * (scl3 * hs);         \
            float iv = fsig(g0), fv = fsig(g1), gv = ftanh(g2), ov = fsig(g3);          \
            cst = fv * cst + iv * gv;                                                   \
            float h = ov * ftanh(cst);                                                  \
            XOUT[((size_t)t_ * BATCH + b) * EDIM + d * HDIM + j] = f2bf(h);             \
            int qz = (int)rintf(h * 127.f);                /* |h|<1: scale 1/127 */     \
            qz = qz > 127 ? 127 : (qz < -127 ? -127 : qz);                              \
            ((signed char*)hq)[(WB) * 256 + j] = (signed char)qz;                       \
            int s2 = ((S) + 2 < T_LEN) ? (S) + 2 : T_LEN - 1;                           \
            int t2 = d ? (T_LEN - 1 - s2) : s2;                                         \
            _Pragma("unroll")                                                           \
            for (int r = 0; r < 4; ++r)                                                 \
                XA[r] = xgp[(size_t)t2 * (BATCH * GDIM) + r * 256];                     \
        }                                                                               \
        bar_lds();                                                                      \
        hs = 1.f / 127.f;                                                               \
    }

    for (int s = 0; s < T_LEN; s += 2) {
        SCAN_SUBSTEP(s,     xe, 0, 1);
        SCAN_SUBSTEP(s + 1, xo, 1, 0);
    }
#undef SCAN_SUBSTEP
}

// ------------- feats[tb][k] = x[tb] . w_out[k] + b_out[k]  (one wave per tb) -------------
__global__ __launch_bounds__(64) void feats_k(const u16* __restrict__ X,      // [16384][512] bf16
                                              const float* __restrict__ Wout, // [7][512] f32
                                              const float* __restrict__ Bout, // [7] f32
                                              float* __restrict__ F) {        // [16384][8] f32
    int tb = blockIdx.x, lane = threadIdx.x;
    uint4 xv = ((const uint4*)(X + (size_t)tb * EDIM))[lane];   // 8 bf16 of x
    float xf[8];
    xf[0] = bflo(xv.x); xf[1] = bfhi(xv.x); xf[2] = bflo(xv.y); xf[3] = bfhi(xv.y);
    xf[4] = bflo(xv.z); xf[5] = bfhi(xv.z); xf[6] = bflo(xv.w); xf[7] = bfhi(xv.w);
    #pragma unroll
    for (int k = 0; k < KTAG; ++k) {
        const float4* wpo = (const float4*)(Wout + (size_t)k * EDIM) + lane * 2;
        float4 wa = wpo[0], wb = wpo[1];
        float p = 0.0f;
        p = fmaf(xf[0], wa.x, p); p = fmaf(xf[1], wa.y, p);
        p = fmaf(xf[2], wa.z, p); p = fmaf(xf[3], wa.w, p);
        p = fmaf(xf[4], wb.x, p); p = fmaf(xf[5], wb.y, p);
        p = fmaf(xf[6], wb.z, p); p = fmaf(xf[7], wb.w, p);
        #pragma unroll
        for (int off = 32; off > 0; off >>= 1) p += __shfl_xor(p, off, 64);
        if (lane == 0) F[tb * 8 + k] = p + Bout[k];
    }
}

// ------------- Viterbi: one wave, lane = batch; byte-packed backpointers -------------
// Backpointers stored TRANSPOSED: BPT[b][t] so the backtrace (256 dependent
// loads per lane) walks contiguous descending addresses (8 hops per 64-B line)
// instead of stride-512B scatter (one fresh L2 line per hop).
__global__ __launch_bounds__(64) void viterbi_k(const float* __restrict__ F,
                                                const float* __restrict__ Trans, // [7][7] next,prev
                                                u64* __restrict__ BPT,           // [64][256]
                                                float* __restrict__ OUT) {       // 16448 floats
    int b = threadIdx.x;
    float tr[KTAG][KTAG];
    #pragma unroll
    for (int n = 0; n < KTAG; ++n)
        #pragma unroll
        for (int p = 0; p < KTAG; ++p)
            tr[n][p] = Trans[n * KTAG + p];

    float v[KTAG];
    #pragma unroll
    for (int k = 0; k < KTAG; ++k) v[k] = (k == 5) ? 0.0f : NEGV;  // START=5

    float cf[KTAG], nf[KTAG];
    #pragma unroll
    for (int n = 0; n < KTAG; ++n) cf[n] = F[b * 8 + n];           // t=0

    for (int t = 0; t < T_LEN; ++t) {
        int tp = (t + 1 < T_LEN) ? t + 1 : t;
        #pragma unroll
        for (int n = 0; n < KTAG; ++n) nf[n] = F[((tp)*BATCH + b) * 8 + n];  // prefetch t+1

        u64 pk = 0;
        float nv[KTAG];
        #pragma unroll
        for (int n = 0; n < KTAG; ++n) {
            float best = v[0] + tr[n][0]; int bi = 0;
            #pragma unroll
            for (int p = 1; p < KTAG; ++p) {
                float s = v[p] + tr[n][p];
                if (s > best) { best = s; bi = p; }   // strict > == np.argmax first-max
            }
            pk |= ((u64)bi) << (8 * n);
            nv[n] = best + cf[n];
        }
        BPT[(b << 8) | t] = pk;
        #pragma unroll
        for (int n = 0; n < KTAG; ++n) { v[n] = nv[n]; cf[n] = nf[n]; }
    }
    float bs = v[0] + tr[6][0]; int tag = 0;          // STOP=6
    #pragma unroll
    for (int k = 1; k < KTAG; ++k) {
        float s = v[k] + tr[6][k];
        if (s > bs) { bs = s; tag = k; }
    }
    OUT[T_LEN * BATCH + b] = bs;                      // path_score [B]
    for (int t = T_LEN - 1; t >= 0; --t) {
        OUT[(size_t)b * T_LEN + t] = (float)tag;      // best_path [B][T]
        tag = (int)((BPT[(b << 8) | t] >> (8 * tag)) & 0xff);
    }
}

extern "C" void kernel_launch(void* const* d_in, const int* in_sizes, int n_in,
                              void* d_out, int out_size, void* d_ws, size_t ws_size,
                              hipStream_t stream) {
    const int*   sent  = (const int*)d_in[0];
    const float* emb   = (const float*)d_in[1];   // [50000][512]
    const float* w_ih  = (const float*)d_in[2];   // [2][2][1024][512]
    const float* w_hh  = (const float*)d_in[3];   // [2][2][1024][256]
    const float* b_ih  = (const float*)d_in[4];   // [2][2][1024]
    const float* b_hh  = (const float*)d_in[5];
    const float* w_out = (const float*)d_in[6];   // [7][512]
    const float* b_out = (const float*)d_in[7];   // [7]
    const float* trans = (const float*)d_in[8];   // [7][7]
    const float* h0    = (const float*)d_in[9];   // [4][64][256]
    const float* c0    = (const float*)d_in[10];
    float* out = (float*)d_out;

    char* ws = (char*)d_ws;
    u16*   xg    = (u16*)(ws);                       // 64 MB  [2][16384][1024] bf16
    u16*   x     = (u16*)(ws + 67108864);            // 16 MB  [16384][512] bf16
    u16*   wihB  = (u16*)(ws + 83886080);            // 4 MB   bf16 w_ih
    uint4* wq    = (uint4*)(ws + 88080384);          // 1 MB   int8 w_hh (packed)
    float* scl   = (float*)(ws + 89128960);          // 16 KB  scales
    float* feats = (float*)(ws + 89145344);          // 512 KB
    u64*   bpt   = (u64*)(ws + 89669632);            // 128 KB

    // allow 82 KB dynamic LDS for the scan (one-time; not a stream op)
    static bool lds_opt_in = false;
    if (!lds_opt_in) {
        (void)hipFuncSetAttribute(reinterpret_cast<const void*>(lstm_scan_i8),
                                  hipFuncAttributeMaxDynamicSharedMemorySize, 82432);
        lds_opt_in = true;
    }

    embed_k<<<16384, 64, 0, stream>>>(sent, emb, x);
    conv_wih<<<1024, 256, 0, stream>>>(w_ih, wihB);
    repack_whh_i8<<<16, 256, 0, stream>>>(w_hh, wq, scl);

    for (int l = 0; l < 2; ++l) {
        gemm_xg<<<dim3(128, 8, 2), 256, 0, stream>>>(
            x, wihB + (size_t)l * 2 * GDIM * EDIM,
            b_ih + (size_t)l * 2 * GDIM, b_hh + (size_t)l * 2 * GDIM, xg);
        // layer l's weights start at ld=2l; WQ ld-stride = 16384 uint4 -> offset l*32768
        lstm_scan_i8<<<128, 1024, 82432, stream>>>(
            xg, wq + (size_t)l * 32768, scl + (size_t)l * 2048,
            h0 + (size_t)l * 2 * BATCH * HDIM, c0 + (size_t)l * 2 * BATCH * HDIM, x);
    }

    feats_k<<<16384, 64, 0, stream>>>(x, w_out, b_out, feats);
    viterbi_k<<<1, 64, 0, stream>>>(feats, trans, bpt, out);
}